// Round 1
// baseline (44.657 us; speedup 1.0000x reference)
//
#include <hip/hip_runtime.h>
#include <math.h>

#define EPSF 1e-5f
#define N_B 16
#define C_CH 128
#define T_LEN 513
#define NI 257
#define NJ 256
#define LN2F 0.69314718055994530942f

// workspace layout (floats)
#define RAM_OFF 0                        // [16][257][256] = 1,052,672
#define PDA_OFF 1052672                  // [16][4][256]   = 16,384
#define DA_OFF  1069056                  // [16][256]      = 4,096
#define RS_OFF  1073152                  // [16][257]      = 4,112
// total 1,077,264 floats = 4,309,056 bytes

// ---------------- Stage 1: RAM[n,i,j] = thresholded exp(mean_c log(e1*e2+eps)^2)
__global__ __launch_bounds__(256) void k_ram(const float* __restrict__ x,
                                             float* __restrict__ ram) {
    const int n  = blockIdx.z;
    const int i0 = blockIdx.y * 32;
    const int j0 = blockIdx.x * 32;
    __shared__ float s1[16][32];
    __shared__ float s2[16][32];
    const int tid = threadIdx.x;
    const int tx = tid & 15, ty = tid >> 4;
    float acc00 = 0.f, acc01 = 0.f, acc10 = 0.f, acc11 = 0.f;
    const float* xn = x + (size_t)n * (C_CH * T_LEN);

    for (int c0 = 0; c0 < C_CH; c0 += 16) {
        {
            // stage s1 (exp(x1)) : 512 values, 2 per thread
            int f = tid;
            int cc = f >> 5, ii = f & 31;
            int i = i0 + ii; int ci = (i < NI) ? (2 * i) : (T_LEN - 1);
            s1[cc][ii] = __expf(xn[(c0 + cc) * T_LEN + ci]);
            f = tid + 256; cc = f >> 5; ii = f & 31;
            i = i0 + ii; ci = (i < NI) ? (2 * i) : (T_LEN - 1);
            s1[cc][ii] = __expf(xn[(c0 + cc) * T_LEN + ci]);
            // stage s2 (exp(-x2)) : j0+jj < 256 always (8*32 tiles exact)
            f = tid; cc = f >> 5; int jj = f & 31;
            s2[cc][jj] = __expf(-xn[(c0 + cc) * T_LEN + 2 * (j0 + jj) + 1]);
            f = tid + 256; cc = f >> 5; jj = f & 31;
            s2[cc][jj] = __expf(-xn[(c0 + cc) * T_LEN + 2 * (j0 + jj) + 1]);
        }
        __syncthreads();
        #pragma unroll
        for (int cc = 0; cc < 16; ++cc) {
            float a0 = s1[cc][2 * ty], a1 = s1[cc][2 * ty + 1];
            float b0 = s2[cc][2 * tx], b1 = s2[cc][2 * tx + 1];
            float l;
            l = __log2f(a0 * b0 + EPSF); acc00 += l * l;
            l = __log2f(a0 * b1 + EPSF); acc01 += l * l;
            l = __log2f(a1 * b0 + EPSF); acc10 += l * l;
            l = __log2f(a1 * b1 + EPSF); acc11 += l * l;
        }
        __syncthreads();
    }
    // Sum_c ln(t)^2 = ln2^2 * acc ; RAM = exp(acc*ln2^2/128) = exp2(acc*ln2/128)
    const float sc = LN2F / 128.0f;
    float r00 = exp2f(acc00 * sc);
    float r01 = exp2f(acc01 * sc);
    float r10 = exp2f(acc10 * sc);
    float r11 = exp2f(acc11 * sc);
    r00 = (r00 < 0.5f) ? 0.f : r00;
    r01 = (r01 < 0.5f) ? 0.f : r01;
    r10 = (r10 < 0.5f) ? 0.f : r10;
    r11 = (r11 < 0.5f) ? 0.f : r11;

    const int i_a = i0 + 2 * ty, i_b = i_a + 1;
    const int j_a = j0 + 2 * tx, j_b = j_a + 1;
    float* rn = ram + (size_t)n * NI * NJ;
    if (i_a < NI) { rn[i_a * NJ + j_a] = r00; rn[i_a * NJ + j_b] = r01; }
    if (i_b < NI) { rn[i_b * NJ + j_a] = r10; rn[i_b * NJ + j_b] = r11; }
}

// ---------------- Stage 2a: partial column sums pda[n][q][j] over i-ranges of 65
__global__ __launch_bounds__(256) void k_colsum(const float* __restrict__ ram,
                                                float* __restrict__ pda) {
    const int n = blockIdx.x;
    const int q = blockIdx.y;
    const int j = threadIdx.x;
    const int ibeg = q * 65;
    const int iend = min(NI, ibeg + 65);
    const float* rn = ram + (size_t)n * NI * NJ;
    float s = 0.f;
    #pragma unroll 4
    for (int i = ibeg; i < iend; ++i) s += rn[i * NJ + j];
    pda[((n * 4) + q) * NJ + j] = s;
}

// ---------------- Stage 2b: da[n][j] = sum_q pda
__global__ __launch_bounds__(256) void k_da(const float* __restrict__ pda,
                                            float* __restrict__ da) {
    const int n = blockIdx.x;
    const int j = threadIdx.x;
    const float* p = pda + (size_t)n * 4 * NJ;
    da[n * NJ + j] = p[j] + p[NJ + j] + p[2 * NJ + j] + p[3 * NJ + j];
}

// ---------------- Stage 3: per row: db + normalized rowsum (wave per row)
__global__ __launch_bounds__(256) void k_rownorm(const float* __restrict__ ram,
                                                 const float* __restrict__ da,
                                                 float* __restrict__ rowsum) {
    const int wave = threadIdx.x >> 6;
    const int lane = threadIdx.x & 63;
    const int row = blockIdx.x * 4 + wave;       // 0 .. 4111 (grid 1028 exact)
    const int n = row / NI;
    const float* r = ram + (size_t)row * NJ;
    float v0 = r[lane], v1 = r[lane + 64], v2 = r[lane + 128], v3 = r[lane + 192];
    float s = v0 + v1 + v2 + v3;
    #pragma unroll
    for (int off = 32; off; off >>= 1) s += __shfl_xor(s, off, 64);
    const float db = s;
    const float* dan = da + n * NJ;
    float t = v0 * rsqrtf(db * dan[lane] + EPSF)
            + v1 * rsqrtf(db * dan[lane + 64] + EPSF)
            + v2 * rsqrtf(db * dan[lane + 128] + EPSF)
            + v3 * rsqrtf(db * dan[lane + 192] + EPSF);
    #pragma unroll
    for (int off = 32; off; off >>= 1) t += __shfl_xor(t, off, 64);
    if (lane == 0) rowsum[row] = t;
}

// ---------------- Stage 4: out[n,c,t] = x[n,c,t] * 2*rowsum[n, t>>1]
__global__ __launch_bounds__(256) void k_apply(const float* __restrict__ x,
                                               const float* __restrict__ rowsum,
                                               float* __restrict__ out) {
    const int idx = blockIdx.x * 256 + threadIdx.x;
    const int total = N_B * C_CH * T_LEN;
    if (idx >= total) return;
    const int t = idx % T_LEN;
    const int n = idx / (C_CH * T_LEN);
    out[idx] = x[idx] * (2.0f * rowsum[n * NI + (t >> 1)]);
}

extern "C" void kernel_launch(void* const* d_in, const int* in_sizes, int n_in,
                              void* d_out, int out_size, void* d_ws, size_t ws_size,
                              hipStream_t stream) {
    const float* x = (const float*)d_in[0];
    float* out = (float*)d_out;
    float* ws = (float*)d_ws;
    float* ram = ws + RAM_OFF;
    float* pda = ws + PDA_OFF;
    float* da  = ws + DA_OFF;
    float* rs  = ws + RS_OFF;

    k_ram<<<dim3(NJ / 32, (NI + 31) / 32, N_B), 256, 0, stream>>>(x, ram);
    k_colsum<<<dim3(N_B, 4), 256, 0, stream>>>(ram, pda);
    k_da<<<N_B, 256, 0, stream>>>(pda, da);
    k_rownorm<<<(N_B * NI) / 4, 256, 0, stream>>>(ram, da, rs);
    const int total = N_B * C_CH * T_LEN;
    k_apply<<<(total + 255) / 256, 256, 0, stream>>>(x, rs, out);
}